// Round 13
// baseline (170.303 us; speedup 1.0000x reference)
//
#include <hip/hip_runtime.h>
#include <hip/hip_fp16.h>

namespace {
constexpr int Bn = 2, Cin = 64, Cout = 64;
constexpr int Dd = 8, Hh = 48, Wd = 48;
constexpr int K = 27;
constexpr int SP = Dd * Hh * Wd;   // 18432
constexpr int PLANE = Hh * Wd;     // 2304
constexpr int NCH = SP / 128;      // 144 128-pos chunks per batch
constexpr int KC = 3;              // K-split factor (main GEMM); KPER = 9
constexpr int KPER = K / KC;
constexpr int CS = 2;              // cin-split factor (offset conv)
}

typedef __attribute__((ext_vector_type(8))) _Float16 half8;
typedef __attribute__((ext_vector_type(4))) float f32x4;

__device__ __forceinline__ unsigned short f2h(float f) {  // RNE float->f16 bits
  return __half_as_ushort(__float2half(f));
}
__device__ __forceinline__ __half2 u2h2(unsigned u) {
  return __builtin_bit_cast(__half2, u);
}
__device__ __forceinline__ unsigned h22u(__half2 h) {
  return __builtin_bit_cast(unsigned, h);
}

// Fused prep: xTh (channels-last f16 x), wTb (main-W A-frag layout),
// wq (offset-W A-frag layout). One launch instead of three.
__global__ __launch_bounds__(256) void k_prep(const float* __restrict__ x,
                                              const float* __restrict__ w,
                                              const float* __restrict__ cw,
                                              unsigned short* __restrict__ xTh,
                                              unsigned short* __restrict__ wTb,
                                              unsigned short* __restrict__ wq) {
  int i = blockIdx.x * 256 + threadIdx.x;   // 2,635,776 total
  if (i < 2359296) {
    // xTh[b][p][c] = x[b][c][p]
    int c = i & 63;
    int rest = i >> 6;
    int p = rest % SP;
    int b = rest / SP;
    xTh[i] = f2h(x[(b * Cin + c) * SP + p]);
  } else if (i < 2359296 + 110592) {
    // wTb[k][mt(4)][s(2)][row(16)][kg(4)][j(8)]
    int i2 = i - 2359296;
    int j = i2 & 7, kg = (i2 >> 3) & 3, row = (i2 >> 5) & 15;
    int s = (i2 >> 9) & 1, mt = (i2 >> 10) & 3, k = i2 >> 12;
    int co = mt * 16 + row, cin = s * 32 + kg * 8 + j;
    wTb[i2] = f2h(w[((size_t)co * Cin + cin) * K + k]);
  } else {
    // wq[tap][cs(2)][mt(6)][row(16)][kg(4)][j(8)]
    int i3 = i - 2469888;                   // < 165,888
    int j = i3 & 7, kg = (i3 >> 3) & 3, row = (i3 >> 5) & 15;
    int rest = i3 >> 9;
    int mt = rest % 6;
    int rest2 = rest / 6;
    int cs = rest2 & 1;
    int tap = rest2 >> 1;
    int ch = mt * 16 + row, cin = cs * 32 + kg * 8 + j;
    float v = (ch < 81) ? cw[((size_t)ch * 64 + cin) * 27 + tap] : 0.f;
    wq[i3] = f2h(v);
  }
}

// Offset conv, barrier-free MFMA (validated round 9). No LDS.
__global__ __launch_bounds__(256) void k_offm3(const unsigned short* __restrict__ xTh,
                                               const unsigned short* __restrict__ wq,
                                               float* __restrict__ opart) {
  const int t = threadIdx.x;
  const int lane = t & 63;
  const int wv = t >> 6;
  const int bid = blockIdx.x;              // cs*576 + nb ; 1152 total
  const int cs = bid / 576;
  const int nb = bid - cs * 576;
  const int n0 = nb * 64;
  const int b = n0 / SP;
  const int sp0 = n0 - b * SP;

  const int q = sp0 + wv * 16 + (lane & 15);   // this lane's output position
  const int d = q / PLANE;
  const int rp = q - d * PLANE;
  const int h = rp / 48;
  const int w = rp - h * 48;

  const unsigned short* xb =
      xTh + ((size_t)b * SP + q) * 64 + cs * 32 + (lane >> 4) * 8;
  const unsigned short* wbase =
      wq + cs * 3072 + (lane & 15) * 32 + (lane >> 4) * 8;

  f32x4 acc[6];
#pragma unroll
  for (int mt = 0; mt < 6; ++mt) acc[mt] = f32x4{0.f, 0.f, 0.f, 0.f};

#pragma unroll
  for (int tap = 0; tap < 27; ++tap) {
    const int kd = tap / 9, kh = (tap % 9) / 3, kw = tap % 3;
    const int dd = d + kd - 1, hh = h + kh - 1, ww = w + kw - 1;
    const bool valid = ((unsigned)dd < 8u) & ((unsigned)hh < 48u) & ((unsigned)ww < 48u);
    const int delta = ((kd - 1) * PLANE + (kh - 1) * 48 + (kw - 1)) * 64;
    half8 bf = {};
    if (valid) bf = *reinterpret_cast<const half8*>(xb + delta);
    const unsigned short* wt = wbase + tap * 6144;
#pragma unroll
    for (int mt = 0; mt < 6; ++mt) {
      half8 af = *reinterpret_cast<const half8*>(wt + mt * 512);
      acc[mt] = __builtin_amdgcn_mfma_f32_16x16x32_f16(af, bf, acc[mt], 0, 0, 0);
    }
  }

  // opart[cs][b][ch][colp], ch<81
  const int colp = sp0 + wv * 16 + (lane & 15);
  float* pp = opart + (size_t)(cs * 2 + b) * 81 * SP;
#pragma unroll
  for (int mt = 0; mt < 6; ++mt) {
#pragma unroll
    for (int reg = 0; reg < 4; ++reg) {
      int ch = mt * 16 + (lane >> 4) * 4 + reg;
      if (ch < 81)
        pp[(size_t)ch * SP + colp] = acc[mt][reg];
    }
  }
}

// offT[b][k][p] = float4(pd, ph, pw, 0) with base grid + conv bias folded in.
// pd = sum_cs opart[cs][b][k][p] + cb[k] + (d + kd - 1), etc.
__global__ __launch_bounds__(256) void k_offT(const float* __restrict__ opart,
                                              const float* __restrict__ cb,
                                              float* __restrict__ offT) {
  int i = blockIdx.x * 256 + threadIdx.x;  // 2*27*4608 = 248,832
  int p4 = i % (SP / 4);
  int k = (i / (SP / 4)) % 27;
  int b = i / ((SP / 4) * 27);
  int kd = k / 9, kh = (k % 9) / 3, kw = k % 3;

  const float4* op4 = (const float4*)opart;
  float4 s[3];
#pragma unroll
  for (int dim = 0; dim < 3; ++dim) {
    int ch = dim * 27 + k;
    size_t base = (size_t)(b * 81 + ch) * (SP / 4) + p4;
    float4 v0 = op4[base];
    float4 v1 = op4[base + (size_t)2 * 81 * (SP / 4)];
    float bb = cb[ch];
    s[dim] = float4{v0.x + v1.x + bb, v0.y + v1.y + bb, v0.z + v1.z + bb,
                    v0.w + v1.w + bb};
  }
  float4* o4 = (float4*)offT + ((size_t)(b * 27 + k) * SP + p4 * 4);
#pragma unroll
  for (int e = 0; e < 4; ++e) {
    int p = p4 * 4 + e;
    int d = p / PLANE;
    int r = p - d * PLANE;
    int h = r / 48;
    int wp = r - h * 48;
    float se0 = (e == 0) ? s[0].x : (e == 1) ? s[0].y : (e == 2) ? s[0].z : s[0].w;
    float se1 = (e == 0) ? s[1].x : (e == 1) ? s[1].y : (e == 2) ? s[1].z : s[1].w;
    float se2 = (e == 0) ? s[2].x : (e == 1) ? s[2].y : (e == 2) ? s[2].z : s[2].w;
    o4[e] = float4{se0 + (float)(d + kd - 1), se1 + (float)(h + kh - 1),
                   se2 + (float)(wp + kw - 1), 0.f};
  }
}

// Fused gather + MFMA GEMM. R12's wave-self-sufficient zero-barrier scheme,
// extended to 2 position-frags per wave (block = 64co x 128pos) so the W
// A-frags load into registers ONCE per k and serve 2 MFMA sets (-22% VMEM
// instr, -50% W L2 traffic). Gather coalescing identical to R9/R12.
__global__ __launch_bounds__(256, 2) void k_mainp(const unsigned short* __restrict__ xTh,
                                                  const float* __restrict__ offT,
                                                  const unsigned short* __restrict__ wTb,
                                                  float* __restrict__ part) {
  __shared__ __align__(16) unsigned scp[4][2][16 * 20];         // per-wave per-frag
  __shared__ __align__(16) unsigned short vals[4][2][16 * 72];

  const int t = threadIdx.x;
  const int lane = t & 63;
  const int wv = t >> 6;
  const int bid = blockIdx.x;                    // kc*288 + j
  const int kc = bid / 288;
  const int j = bid - kc * 288;
  const int tl = (j & 7) * 36 + (j >> 3);        // XCD-contiguous chunks
  const int b = tl / NCH;
  const int chunk = tl - b * NCH;
  const int p0 = chunk * 128;

  const char* xb8 = (const char*)(xTh + (size_t)b * SP * 64);
  const float4* offTb = (const float4*)offT + (size_t)b * 27 * SP;

  const int posl = lane & 15;
  const int quad = lane >> 4;
  const int sf = quad >> 1;      // setup: frag this lane serves
  const int cg = quad & 1;       // setup: corner group (4 corners)
  const int spos = p0 + wv * 32 + sf * 16 + posl;

  const int gpl0 = lane >> 3;    // gather: row base 0..7
  const int gchg = lane & 7;     // gather: 8-channel chunk

  f32x4 acc[2][4];
#pragma unroll
  for (int f = 0; f < 2; ++f)
#pragma unroll
    for (int mt = 0; mt < 4; ++mt) acc[f][mt] = f32x4{0.f, 0.f, 0.f, 0.f};

  for (int kk = 0; kk < KPER; ++kk) {
    const int k = kc * KPER + kk;
    // ---- W register cache for this k (reused by both frags)
    half8 af[2][4];
    {
      const unsigned short* wk = wTb + (size_t)k * 4096 + posl * 32 + quad * 8;
#pragma unroll
      for (int s = 0; s < 2; ++s)
#pragma unroll
        for (int mt = 0; mt < 4; ++mt)
          af[s][mt] = *reinterpret_cast<const half8*>(wk + mt * 1024 + s * 512);
    }
    // ---- setup: 4 corners (cg*4..cg*4+3) of position spos, frag sf
    {
      float4 o = offTb[(size_t)k * SP + spos];
      float df = floorf(o.x), hf = floorf(o.y), wf = floorf(o.z);
      float fd = o.x - df, fh = o.y - hf, fw = o.z - wf;
      int d0 = (int)df, h0 = (int)hf, w0i = (int)wf;
      unsigned pk[8];
#pragma unroll
      for (int cc = 0; cc < 4; ++cc) {
        int c = cg * 4 + cc;
        int cd = c >> 2, ch = (c >> 1) & 1, cwb = c & 1;
        int di = d0 + cd, hi = h0 + ch, wi = w0i + cwb;
        bool v = ((unsigned)di < 8u) && ((unsigned)hi < 48u) && ((unsigned)wi < 48u);
        float wg = (cd ? fd : 1.f - fd) * (ch ? fh : 1.f - fh) * (cwb ? fw : 1.f - fw);
        int dic = min(max(di, 0), 7), hic = min(max(hi, 0), 47), wic = min(max(wi, 0), 47);
        unsigned hs = (unsigned)f2h(v ? wg : 0.f);
        pk[cc * 2] = (unsigned)((dic * 48 + hic) * 48 + wic);
        pk[cc * 2 + 1] = hs | (hs << 16);
      }
      unsigned* row = &scp[wv][sf][posl * 20];
      *reinterpret_cast<uint4*>(row + cg * 8) = uint4{pk[0], pk[1], pk[2], pk[3]};
      *reinterpret_cast<uint4*>(row + cg * 8 + 4) = uint4{pk[4], pk[5], pk[6], pk[7]};
    }
    // ---- gather: 4 units/lane (2 frags x 2 rows), same-wave LDS ordering
#pragma unroll
    for (int u = 0; u < 4; ++u) {
      const int uf = u >> 1;
      const int pl = gpl0 + (u & 1) * 8;
      const unsigned* sp = &scp[wv][uf][pl * 20];
      const uint4 m0 = *reinterpret_cast<const uint4*>(sp + 0);
      const uint4 m1 = *reinterpret_cast<const uint4*>(sp + 4);
      const uint4 m2 = *reinterpret_cast<const uint4*>(sp + 8);
      const uint4 m3 = *reinterpret_cast<const uint4*>(sp + 12);
      const int cof = gchg << 4;
      uint4 q0 = *reinterpret_cast<const uint4*>(xb8 + (((size_t)m0.x << 7) + cof));
      uint4 q1 = *reinterpret_cast<const uint4*>(xb8 + (((size_t)m0.z << 7) + cof));
      uint4 q2 = *reinterpret_cast<const uint4*>(xb8 + (((size_t)m1.x << 7) + cof));
      uint4 q3 = *reinterpret_cast<const uint4*>(xb8 + (((size_t)m1.z << 7) + cof));
      uint4 q4 = *reinterpret_cast<const uint4*>(xb8 + (((size_t)m2.x << 7) + cof));
      uint4 q5 = *reinterpret_cast<const uint4*>(xb8 + (((size_t)m2.z << 7) + cof));
      uint4 q6 = *reinterpret_cast<const uint4*>(xb8 + (((size_t)m3.x << 7) + cof));
      uint4 q7 = *reinterpret_cast<const uint4*>(xb8 + (((size_t)m3.z << 7) + cof));
      __half2 a2[4];
#pragma unroll
      for (int e = 0; e < 4; ++e) a2[e] = u2h2(0u);
      __half2 w0 = u2h2(m0.y), w1 = u2h2(m0.w), w2 = u2h2(m1.y), w3 = u2h2(m1.w);
      __half2 w4 = u2h2(m2.y), w5 = u2h2(m2.w), w6 = u2h2(m3.y), w7 = u2h2(m3.w);
      a2[0] = __hfma2(u2h2(q0.x), w0, a2[0]); a2[1] = __hfma2(u2h2(q0.y), w0, a2[1]);
      a2[2] = __hfma2(u2h2(q0.z), w0, a2[2]); a2[3] = __hfma2(u2h2(q0.w), w0, a2[3]);
      a2[0] = __hfma2(u2h2(q1.x), w1, a2[0]); a2[1] = __hfma2(u2h2(q1.y), w1, a2[1]);
      a2[2] = __hfma2(u2h2(q1.z), w1, a2[2]); a2[3] = __hfma2(u2h2(q1.w), w1, a2[3]);
      a2[0] = __hfma2(u2h2(q2.x), w2, a2[0]); a2[1] = __hfma2(u2h2(q2.y), w2, a2[1]);
      a2[2] = __hfma2(u2h2(q2.z), w2, a2[2]); a2[3] = __hfma2(u2h2(q2.w), w2, a2[3]);
      a2[0] = __hfma2(u2h2(q3.x), w3, a2[0]); a2[1] = __hfma2(u2h2(q3.y), w3, a2[1]);
      a2[2] = __hfma2(u2h2(q3.z), w3, a2[2]); a2[3] = __hfma2(u2h2(q3.w), w3, a2[3]);
      a2[0] = __hfma2(u2h2(q4.x), w4, a2[0]); a2[1] = __hfma2(u2h2(q4.y), w4, a2[1]);
      a2[2] = __hfma2(u2h2(q4.z), w4, a2[2]); a2[3] = __hfma2(u2h2(q4.w), w4, a2[3]);
      a2[0] = __hfma2(u2h2(q5.x), w5, a2[0]); a2[1] = __hfma2(u2h2(q5.y), w5, a2[1]);
      a2[2] = __hfma2(u2h2(q5.z), w5, a2[2]); a2[3] = __hfma2(u2h2(q5.w), w5, a2[3]);
      a2[0] = __hfma2(u2h2(q6.x), w6, a2[0]); a2[1] = __hfma2(u2h2(q6.y), w6, a2[1]);
      a2[2] = __hfma2(u2h2(q6.z), w6, a2[2]); a2[3] = __hfma2(u2h2(q6.w), w6, a2[3]);
      a2[0] = __hfma2(u2h2(q7.x), w7, a2[0]); a2[1] = __hfma2(u2h2(q7.y), w7, a2[1]);
      a2[2] = __hfma2(u2h2(q7.z), w7, a2[2]); a2[3] = __hfma2(u2h2(q7.w), w7, a2[3]);
      *reinterpret_cast<uint4*>(&vals[wv][uf][pl * 72 + gchg * 8]) =
          uint4{h22u(a2[0]), h22u(a2[1]), h22u(a2[2]), h22u(a2[3])};
    }
    // ---- MFMA: both frags reuse the register-cached W
#pragma unroll
    for (int f = 0; f < 2; ++f) {
#pragma unroll
      for (int s = 0; s < 2; ++s) {
        half8 bfr = *reinterpret_cast<const half8*>(
            &vals[wv][f][posl * 72 + s * 32 + quad * 8]);
#pragma unroll
        for (int mt = 0; mt < 4; ++mt)
          acc[f][mt] = __builtin_amdgcn_mfma_f32_16x16x32_f16(af[s][mt], bfr,
                                                              acc[f][mt], 0, 0, 0);
      }
    }
  }

  // part[kc][b][chunk][co][128 pos]; co = mt*16+quad*4+reg
  float* pp = part + ((size_t)(kc * 2 + b) * NCH + chunk) * 8192;
#pragma unroll
  for (int f = 0; f < 2; ++f)
#pragma unroll
    for (int mt = 0; mt < 4; ++mt)
#pragma unroll
      for (int reg = 0; reg < 4; ++reg) {
        int co = mt * 16 + quad * 4 + reg;
        pp[co * 128 + wv * 32 + f * 16 + posl] = acc[f][mt][reg];
      }
}

// out[b][co][p] = bias[co] + sum_kc part[kc][b][chunk][co][pos]  (float4)
__global__ __launch_bounds__(256) void k_red(const float* __restrict__ part,
                                             const float* __restrict__ bias,
                                             float* __restrict__ out) {
  int i = blockIdx.x * 256 + threadIdx.x;  // 589,824 float4 units
  int p4 = i % (SP / 4);
  int co = (i / (SP / 4)) & 63;
  int b = i / ((SP / 4) * 64);
  int p = p4 * 4;
  int chunk = p >> 7, pos = p & 127;
  size_t base = ((size_t)(b * NCH) + chunk) * 8192 + co * 128 + pos;
  float4 s = *reinterpret_cast<const float4*>(&part[base]);
#pragma unroll
  for (int kc = 1; kc < KC; ++kc) {
    float4 v = *reinterpret_cast<const float4*>(
        &part[base + (size_t)kc * 2 * NCH * 8192]);
    s.x += v.x; s.y += v.y; s.z += v.z; s.w += v.w;
  }
  float bb = bias[co];
  s.x += bb; s.y += bb; s.z += bb; s.w += bb;
  *reinterpret_cast<float4*>(&out[((size_t)(b * 64 + co)) * SP + p]) = s;
}

extern "C" void kernel_launch(void* const* d_in, const int* in_sizes, int n_in,
                              void* d_out, int out_size, void* d_ws, size_t ws_size,
                              hipStream_t stream) {
  const float* x = (const float*)d_in[0];
  const float* cw = (const float*)d_in[1];
  const float* cb = (const float*)d_in[2];
  const float* w = (const float*)d_in[3];
  const float* bias = (const float*)d_in[4];
  float* out = (float*)d_out;

  char* ws = (char*)d_ws;
  float* offT = (float*)ws;                                  // 15,925,248 B
  unsigned short* xTh = (unsigned short*)(ws + 15925248);    //  4,718,592 B
  unsigned short* wTb = (unsigned short*)(ws + 20643840);    //    221,184 B
  unsigned short* wq = (unsigned short*)(ws + 20865024);     //    331,776 B
  float* part = (float*)(ws + 21196800);                     // 28,311,552 B
  float* opart = (float*)(ws + 49508352);                    // 23,887,872 B

  hipLaunchKernelGGL(k_prep, dim3(10296), dim3(256), 0, stream, x, w, cw, xTh, wTb, wq);
  hipLaunchKernelGGL(k_offm3, dim3(CS * 576), dim3(256), 0, stream, xTh, wq, opart);
  hipLaunchKernelGGL(k_offT, dim3(972), dim3(256), 0, stream, opart, cb, offT);
  hipLaunchKernelGGL(k_mainp, dim3(KC * 288), dim3(256), 0, stream, xTh, offT, wTb, part);
  hipLaunchKernelGGL(k_red, dim3(2304), dim3(256), 0, stream, part, bias, out);
}

// Round 14
// 162.996 us; speedup vs baseline: 1.0448x; 1.0448x over previous
//
#include <hip/hip_runtime.h>
#include <hip/hip_fp16.h>

namespace {
constexpr int Bn = 2, Cin = 64, Cout = 64;
constexpr int Dd = 8, Hh = 48, Wd = 48;
constexpr int K = 27;
constexpr int SP = Dd * Hh * Wd;   // 18432
constexpr int PLANE = Hh * Wd;     // 2304
constexpr int NT32 = SP / 32;      // 576 32-pos tiles per batch
constexpr int KC = 3;              // K-split factor (main GEMM); KPER = 9
constexpr int KPER = K / KC;
constexpr int CS = 2;              // cin-split factor (offset conv)
}

typedef __attribute__((ext_vector_type(8))) _Float16 half8;
typedef __attribute__((ext_vector_type(4))) float f32x4;

__device__ __forceinline__ unsigned short f2h(float f) {  // RNE float->f16 bits
  return __half_as_ushort(__float2half(f));
}
__device__ __forceinline__ __half2 u2h2(unsigned u) {
  return __builtin_bit_cast(__half2, u);
}
__device__ __forceinline__ unsigned h22u(__half2 h) {
  return __builtin_bit_cast(unsigned, h);
}

// Fused prep: xTh (channels-last f16 x), wTb (main-W A-frag layout),
// wq (offset-W A-frag layout).
__global__ __launch_bounds__(256) void k_prep(const float* __restrict__ x,
                                              const float* __restrict__ w,
                                              const float* __restrict__ cw,
                                              unsigned short* __restrict__ xTh,
                                              unsigned short* __restrict__ wTb,
                                              unsigned short* __restrict__ wq) {
  int i = blockIdx.x * 256 + threadIdx.x;   // 2,635,776 total
  if (i < 2359296) {
    int c = i & 63;
    int rest = i >> 6;
    int p = rest % SP;
    int b = rest / SP;
    xTh[i] = f2h(x[(b * Cin + c) * SP + p]);
  } else if (i < 2359296 + 110592) {
    int i2 = i - 2359296;
    int j = i2 & 7, kg = (i2 >> 3) & 3, row = (i2 >> 5) & 15;
    int s = (i2 >> 9) & 1, mt = (i2 >> 10) & 3, k = i2 >> 12;
    int co = mt * 16 + row, cin = s * 32 + kg * 8 + j;
    wTb[i2] = f2h(w[((size_t)co * Cin + cin) * K + k]);
  } else {
    int i3 = i - 2469888;                   // < 165,888
    int j = i3 & 7, kg = (i3 >> 3) & 3, row = (i3 >> 5) & 15;
    int rest = i3 >> 9;
    int mt = rest % 6;
    int rest2 = rest / 6;
    int cs = rest2 & 1;
    int tap = rest2 >> 1;
    int ch = mt * 16 + row, cin = cs * 32 + kg * 8 + j;
    float v = (ch < 81) ? cw[((size_t)ch * 64 + cin) * 27 + tap] : 0.f;
    wq[i3] = f2h(v);
  }
}

// Offset conv, barrier-free MFMA (validated round 9). No LDS. UNCHANGED this
// round — next round's counters will expose its true cost for the first time.
__global__ __launch_bounds__(256) void k_offm3(const unsigned short* __restrict__ xTh,
                                               const unsigned short* __restrict__ wq,
                                               float* __restrict__ opart) {
  const int t = threadIdx.x;
  const int lane = t & 63;
  const int wv = t >> 6;
  const int bid = blockIdx.x;              // cs*576 + nb ; 1152 total
  const int cs = bid / 576;
  const int nb = bid - cs * 576;
  const int n0 = nb * 64;
  const int b = n0 / SP;
  const int sp0 = n0 - b * SP;

  const int q = sp0 + wv * 16 + (lane & 15);
  const int d = q / PLANE;
  const int rp = q - d * PLANE;
  const int h = rp / 48;
  const int w = rp - h * 48;

  const unsigned short* xb =
      xTh + ((size_t)b * SP + q) * 64 + cs * 32 + (lane >> 4) * 8;
  const unsigned short* wbase =
      wq + cs * 3072 + (lane & 15) * 32 + (lane >> 4) * 8;

  f32x4 acc[6];
#pragma unroll
  for (int mt = 0; mt < 6; ++mt) acc[mt] = f32x4{0.f, 0.f, 0.f, 0.f};

#pragma unroll
  for (int tap = 0; tap < 27; ++tap) {
    const int kd = tap / 9, kh = (tap % 9) / 3, kw = tap % 3;
    const int dd = d + kd - 1, hh = h + kh - 1, ww = w + kw - 1;
    const bool valid = ((unsigned)dd < 8u) & ((unsigned)hh < 48u) & ((unsigned)ww < 48u);
    const int delta = ((kd - 1) * PLANE + (kh - 1) * 48 + (kw - 1)) * 64;
    half8 bf = {};
    if (valid) bf = *reinterpret_cast<const half8*>(xb + delta);
    const unsigned short* wt = wbase + tap * 6144;
#pragma unroll
    for (int mt = 0; mt < 6; ++mt) {
      half8 af = *reinterpret_cast<const half8*>(wt + mt * 512);
      acc[mt] = __builtin_amdgcn_mfma_f32_16x16x32_f16(af, bf, acc[mt], 0, 0, 0);
    }
  }

  const int colp = sp0 + wv * 16 + (lane & 15);
  float* pp = opart + (size_t)(cs * 2 + b) * 81 * SP;
#pragma unroll
  for (int mt = 0; mt < 6; ++mt) {
#pragma unroll
    for (int reg = 0; reg < 4; ++reg) {
      int ch = mt * 16 + (lane >> 4) * 4 + reg;
      if (ch < 81)
        pp[(size_t)ch * SP + colp] = acc[mt][reg];
    }
  }
}

// offT[b][k][p] = float4(pd, ph, pw, 0) with base grid + conv bias folded in.
__global__ __launch_bounds__(256) void k_offT(const float* __restrict__ opart,
                                              const float* __restrict__ cb,
                                              float* __restrict__ offT) {
  int i = blockIdx.x * 256 + threadIdx.x;  // 2*27*4608 = 248,832
  int p4 = i % (SP / 4);
  int k = (i / (SP / 4)) % 27;
  int b = i / ((SP / 4) * 27);
  int kd = k / 9, kh = (k % 9) / 3, kw = k % 3;

  const float4* op4 = (const float4*)opart;
  float4 s[3];
#pragma unroll
  for (int dim = 0; dim < 3; ++dim) {
    int ch = dim * 27 + k;
    size_t base = (size_t)(b * 81 + ch) * (SP / 4) + p4;
    float4 v0 = op4[base];
    float4 v1 = op4[base + (size_t)2 * 81 * (SP / 4)];
    float bb = cb[ch];
    s[dim] = float4{v0.x + v1.x + bb, v0.y + v1.y + bb, v0.z + v1.z + bb,
                    v0.w + v1.w + bb};
  }
  float4* o4 = (float4*)offT + ((size_t)(b * 27 + k) * SP + p4 * 4);
#pragma unroll
  for (int e = 0; e < 4; ++e) {
    int p = p4 * 4 + e;
    int d = p / PLANE;
    int r = p - d * PLANE;
    int h = r / 48;
    int wp = r - h * 48;
    float se0 = (e == 0) ? s[0].x : (e == 1) ? s[0].y : (e == 2) ? s[0].z : s[0].w;
    float se1 = (e == 0) ? s[1].x : (e == 1) ? s[1].y : (e == 2) ? s[1].z : s[1].w;
    float se2 = (e == 0) ? s[2].x : (e == 1) ? s[2].y : (e == 2) ? s[2].z : s[2].w;
    o4[e] = float4{se0 + (float)(d + kd - 1), se1 + (float)(h + kh - 1),
                   se2 + (float)(wp + kw - 1), 0.f};
  }
}

// Fused gather + MFMA GEMM. R12's proven wave-self-sufficient zero-barrier
// structure (VGPR ~28) + R13's offT pre-fold, repackaged as 2-wave blocks:
// grid 3456 = 13.5 blocks/CU for finer scheduling + higher occupancy.
__global__ __launch_bounds__(128, 8) void k_mainp(const unsigned short* __restrict__ xTh,
                                                  const float* __restrict__ offT,
                                                  const unsigned short* __restrict__ wTb,
                                                  float* __restrict__ part) {
  __shared__ __align__(16) unsigned scp[2][16 * 20];         // per-wave [pos16][20w]
  __shared__ __align__(16) unsigned short vals[2][16 * 72];  // per-wave [pos16][cin]

  const int t = threadIdx.x;
  const int lane = t & 63;
  const int wv = t >> 6;                         // 0..1
  const int bid = blockIdx.x;                    // kc*1152 + j
  const int kc = bid / 1152;
  const int j = bid - kc * 1152;
  const int tl = (j & 7) * 144 + (j >> 3);       // XCD-contiguous tiles
  const int b = tl / NT32;
  const int tile = tl - b * NT32;
  const int p0 = tile * 32;

  const char* xb8 = (const char*)(xTh + (size_t)b * SP * 64);
  const float4* offTb = (const float4*)offT + (size_t)b * 27 * SP;

  const int posl = lane & 15;
  const int quad = lane >> 4;
  const int p = p0 + wv * 16 + posl;             // this lane's position
  unsigned* myrow = &scp[wv][posl * 20];

  const int gpl0 = lane >> 3;   // gather: row base 0..7
  const int gchg = lane & 7;    // gather: 8-channel chunk

  f32x4 acc[4];
#pragma unroll
  for (int mt = 0; mt < 4; ++mt) acc[mt] = f32x4{0.f, 0.f, 0.f, 0.f};

  for (int kk = 0; kk < KPER; ++kk) {
    const int k = kc * KPER + kk;
    // ---- setup: corners 2*quad, 2*quad+1 of position p (offT pre-folded)
    {
      float4 o = offTb[(size_t)k * SP + p];
      float df = floorf(o.x), hf = floorf(o.y), wf = floorf(o.z);
      float fd = o.x - df, fh = o.y - hf, fw = o.z - wf;
      int d0 = (int)df, h0 = (int)hf, w0i = (int)wf;
      unsigned pk[4];
#pragma unroll
      for (int cc = 0; cc < 2; ++cc) {
        int c = quad * 2 + cc;
        int cd = c >> 2, ch = (c >> 1) & 1, cwb = c & 1;
        int di = d0 + cd, hi = h0 + ch, wi = w0i + cwb;
        bool v = ((unsigned)di < 8u) && ((unsigned)hi < 48u) && ((unsigned)wi < 48u);
        float wg = (cd ? fd : 1.f - fd) * (ch ? fh : 1.f - fh) * (cwb ? fw : 1.f - fw);
        int dic = min(max(di, 0), 7), hic = min(max(hi, 0), 47), wic = min(max(wi, 0), 47);
        unsigned hs = (unsigned)f2h(v ? wg : 0.f);
        pk[cc * 2] = (unsigned)((dic * 48 + hic) * 48 + wic);
        pk[cc * 2 + 1] = hs | (hs << 16);
      }
      *reinterpret_cast<uint4*>(myrow + quad * 4) = uint4{pk[0], pk[1], pk[2], pk[3]};
    }
    // ---- gather: 2 units/lane, rows gpl0 and gpl0+8 (same-wave LDS ordering)
#pragma unroll
    for (int u = 0; u < 2; ++u) {
      const int pl = gpl0 + u * 8;
      const unsigned* sp = &scp[wv][pl * 20];
      const uint4 m0 = *reinterpret_cast<const uint4*>(sp + 0);
      const uint4 m1 = *reinterpret_cast<const uint4*>(sp + 4);
      const uint4 m2 = *reinterpret_cast<const uint4*>(sp + 8);
      const uint4 m3 = *reinterpret_cast<const uint4*>(sp + 12);
      const int cof = gchg << 4;
      uint4 q0 = *reinterpret_cast<const uint4*>(xb8 + (((size_t)m0.x << 7) + cof));
      uint4 q1 = *reinterpret_cast<const uint4*>(xb8 + (((size_t)m0.z << 7) + cof));
      uint4 q2 = *reinterpret_cast<const uint4*>(xb8 + (((size_t)m1.x << 7) + cof));
      uint4 q3 = *reinterpret_cast<const uint4*>(xb8 + (((size_t)m1.z << 7) + cof));
      uint4 q4 = *reinterpret_cast<const uint4*>(xb8 + (((size_t)m2.x << 7) + cof));
      uint4 q5 = *reinterpret_cast<const uint4*>(xb8 + (((size_t)m2.z << 7) + cof));
      uint4 q6 = *reinterpret_cast<const uint4*>(xb8 + (((size_t)m3.x << 7) + cof));
      uint4 q7 = *reinterpret_cast<const uint4*>(xb8 + (((size_t)m3.z << 7) + cof));
      __half2 a2[4];
#pragma unroll
      for (int e = 0; e < 4; ++e) a2[e] = u2h2(0u);
      __half2 w0 = u2h2(m0.y), w1 = u2h2(m0.w), w2 = u2h2(m1.y), w3 = u2h2(m1.w);
      __half2 w4 = u2h2(m2.y), w5 = u2h2(m2.w), w6 = u2h2(m3.y), w7 = u2h2(m3.w);
      a2[0] = __hfma2(u2h2(q0.x), w0, a2[0]); a2[1] = __hfma2(u2h2(q0.y), w0, a2[1]);
      a2[2] = __hfma2(u2h2(q0.z), w0, a2[2]); a2[3] = __hfma2(u2h2(q0.w), w0, a2[3]);
      a2[0] = __hfma2(u2h2(q1.x), w1, a2[0]); a2[1] = __hfma2(u2h2(q1.y), w1, a2[1]);
      a2[2] = __hfma2(u2h2(q1.z), w1, a2[2]); a2[3] = __hfma2(u2h2(q1.w), w1, a2[3]);
      a2[0] = __hfma2(u2h2(q2.x), w2, a2[0]); a2[1] = __hfma2(u2h2(q2.y), w2, a2[1]);
      a2[2] = __hfma2(u2h2(q2.z), w2, a2[2]); a2[3] = __hfma2(u2h2(q2.w), w2, a2[3]);
      a2[0] = __hfma2(u2h2(q3.x), w3, a2[0]); a2[1] = __hfma2(u2h2(q3.y), w3, a2[1]);
      a2[2] = __hfma2(u2h2(q3.z), w3, a2[2]); a2[3] = __hfma2(u2h2(q3.w), w3, a2[3]);
      a2[0] = __hfma2(u2h2(q4.x), w4, a2[0]); a2[1] = __hfma2(u2h2(q4.y), w4, a2[1]);
      a2[2] = __hfma2(u2h2(q4.z), w4, a2[2]); a2[3] = __hfma2(u2h2(q4.w), w4, a2[3]);
      a2[0] = __hfma2(u2h2(q5.x), w5, a2[0]); a2[1] = __hfma2(u2h2(q5.y), w5, a2[1]);
      a2[2] = __hfma2(u2h2(q5.z), w5, a2[2]); a2[3] = __hfma2(u2h2(q5.w), w5, a2[3]);
      a2[0] = __hfma2(u2h2(q6.x), w6, a2[0]); a2[1] = __hfma2(u2h2(q6.y), w6, a2[1]);
      a2[2] = __hfma2(u2h2(q6.z), w6, a2[2]); a2[3] = __hfma2(u2h2(q6.w), w6, a2[3]);
      a2[0] = __hfma2(u2h2(q7.x), w7, a2[0]); a2[1] = __hfma2(u2h2(q7.y), w7, a2[1]);
      a2[2] = __hfma2(u2h2(q7.z), w7, a2[2]); a2[3] = __hfma2(u2h2(q7.w), w7, a2[3]);
      *reinterpret_cast<uint4*>(&vals[wv][pl * 72 + gchg * 8]) =
          uint4{h22u(a2[0]), h22u(a2[1]), h22u(a2[2]), h22u(a2[3])};
    }
    // ---- MFMA: B-frag from this wave's own vals (same-wave ordering)
    {
      const unsigned short* wk = wTb + (size_t)k * 4096;
#pragma unroll
      for (int s = 0; s < 2; ++s) {
        half8 bfr = *reinterpret_cast<const half8*>(
            &vals[wv][posl * 72 + s * 32 + quad * 8]);
#pragma unroll
        for (int mt = 0; mt < 4; ++mt) {
          half8 afr = *reinterpret_cast<const half8*>(
              wk + mt * 1024 + s * 512 + posl * 32 + quad * 8);
          acc[mt] = __builtin_amdgcn_mfma_f32_16x16x32_f16(afr, bfr, acc[mt], 0, 0, 0);
        }
      }
    }
  }

  // part[kc][b][tile32][co][32]; co = mt*16+quad*4+reg, pos = wv*16+posl
  float* pp = part + ((size_t)(kc * 2 + b) * NT32 + tile) * 2048;
#pragma unroll
  for (int mt = 0; mt < 4; ++mt) {
#pragma unroll
    for (int reg = 0; reg < 4; ++reg) {
      int co = mt * 16 + quad * 4 + reg;
      pp[co * 32 + wv * 16 + posl] = acc[mt][reg];
    }
  }
}

// out[b][co][p] = bias[co] + sum_kc part[kc][b][tile32][co][pos]  (float4)
__global__ __launch_bounds__(256) void k_red(const float* __restrict__ part,
                                             const float* __restrict__ bias,
                                             float* __restrict__ out) {
  int i = blockIdx.x * 256 + threadIdx.x;  // 589,824 float4 units
  int p4 = i % (SP / 4);
  int co = (i / (SP / 4)) & 63;
  int b = i / ((SP / 4) * 64);
  int p = p4 * 4;
  int tile = p >> 5, pos = p & 31;
  size_t base = ((size_t)(b * NT32) + tile) * 2048 + co * 32 + pos;
  float4 s = *reinterpret_cast<const float4*>(&part[base]);
#pragma unroll
  for (int kc = 1; kc < KC; ++kc) {
    float4 v = *reinterpret_cast<const float4*>(
        &part[base + (size_t)kc * 2 * NT32 * 2048]);
    s.x += v.x; s.y += v.y; s.z += v.z; s.w += v.w;
  }
  float bb = bias[co];
  s.x += bb; s.y += bb; s.z += bb; s.w += bb;
  *reinterpret_cast<float4*>(&out[((size_t)(b * 64 + co)) * SP + p]) = s;
}

extern "C" void kernel_launch(void* const* d_in, const int* in_sizes, int n_in,
                              void* d_out, int out_size, void* d_ws, size_t ws_size,
                              hipStream_t stream) {
  const float* x = (const float*)d_in[0];
  const float* cw = (const float*)d_in[1];
  const float* cb = (const float*)d_in[2];
  const float* w = (const float*)d_in[3];
  const float* bias = (const float*)d_in[4];
  float* out = (float*)d_out;

  char* ws = (char*)d_ws;
  float* offT = (float*)ws;                                  // 15,925,248 B
  unsigned short* xTh = (unsigned short*)(ws + 15925248);    //  4,718,592 B
  unsigned short* wTb = (unsigned short*)(ws + 20643840);    //    221,184 B
  unsigned short* wq = (unsigned short*)(ws + 20865024);     //    331,776 B
  float* part = (float*)(ws + 21196800);                     // 28,311,552 B
  float* opart = (float*)(ws + 49508352);                    // 23,887,872 B

  hipLaunchKernelGGL(k_prep, dim3(10296), dim3(256), 0, stream, x, w, cw, xTh, wTb, wq);
  hipLaunchKernelGGL(k_offm3, dim3(CS * 576), dim3(256), 0, stream, xTh, wq, opart);
  hipLaunchKernelGGL(k_offT, dim3(972), dim3(256), 0, stream, opart, cb, offT);
  hipLaunchKernelGGL(k_mainp, dim3(KC * 1152), dim3(128), 0, stream, xTh, offT, wTb, part);
  hipLaunchKernelGGL(k_red, dim3(2304), dim3(256), 0, stream, part, bias, out);
}

// Round 15
// 158.903 us; speedup vs baseline: 1.0717x; 1.0258x over previous
//
#include <hip/hip_runtime.h>
#include <hip/hip_fp16.h>

namespace {
constexpr int Bn = 2, Cin = 64, Cout = 64;
constexpr int Dd = 8, Hh = 48, Wd = 48;
constexpr int K = 27;
constexpr int SP = Dd * Hh * Wd;   // 18432
constexpr int PLANE = Hh * Wd;     // 2304
constexpr int NT32 = SP / 32;      // 576 32-pos tiles per batch
constexpr int KC = 3;              // K-split factor (main GEMM); KPER = 9
constexpr int KPER = K / KC;
constexpr int CS = 2;              // cin-split factor (offset conv)
}

typedef __attribute__((ext_vector_type(8))) _Float16 half8;
typedef __attribute__((ext_vector_type(4))) float f32x4;

__device__ __forceinline__ unsigned short f2h(float f) {  // RNE float->f16 bits
  return __half_as_ushort(__float2half(f));
}
__device__ __forceinline__ __half2 u2h2(unsigned u) {
  return __builtin_bit_cast(__half2, u);
}
__device__ __forceinline__ unsigned h22u(__half2 h) {
  return __builtin_bit_cast(unsigned, h);
}

// Fused prep: xTh (channels-last f16 x), wTb (main-W A-frag layout),
// wq (offset-W A-frag layout).
__global__ __launch_bounds__(256) void k_prep(const float* __restrict__ x,
                                              const float* __restrict__ w,
                                              const float* __restrict__ cw,
                                              unsigned short* __restrict__ xTh,
                                              unsigned short* __restrict__ wTb,
                                              unsigned short* __restrict__ wq) {
  int i = blockIdx.x * 256 + threadIdx.x;   // 2,635,776 total
  if (i < 2359296) {
    int c = i & 63;
    int rest = i >> 6;
    int p = rest % SP;
    int b = rest / SP;
    xTh[i] = f2h(x[(b * Cin + c) * SP + p]);
  } else if (i < 2359296 + 110592) {
    int i2 = i - 2359296;
    int j = i2 & 7, kg = (i2 >> 3) & 3, row = (i2 >> 5) & 15;
    int s = (i2 >> 9) & 1, mt = (i2 >> 10) & 3, k = i2 >> 12;
    int co = mt * 16 + row, cin = s * 32 + kg * 8 + j;
    wTb[i2] = f2h(w[((size_t)co * Cin + cin) * K + k]);
  } else {
    int i3 = i - 2469888;                   // < 165,888
    int j = i3 & 7, kg = (i3 >> 3) & 3, row = (i3 >> 5) & 15;
    int rest = i3 >> 9;
    int mt = rest % 6;
    int rest2 = rest / 6;
    int cs = rest2 & 1;
    int tap = rest2 >> 1;
    int ch = mt * 16 + row, cin = cs * 32 + kg * 8 + j;
    float v = (ch < 81) ? cw[((size_t)ch * 64 + cin) * 27 + tap] : 0.f;
    wq[i3] = f2h(v);
  }
}

// Offset conv, barrier-free MFMA. v2: (a) B-loads are UNCONDITIONAL from a
// clamped row address, masked to zero afterwards -> hoistable/pipelinable
// (the old `if (valid)` guard blocked scheduling past 27 exec-mask branches);
// (b) 128-thread blocks, grid 2304 = 9 blocks/CU uniform (was 4.5).
__global__ __launch_bounds__(128) void k_offm3(const unsigned short* __restrict__ xTh,
                                               const unsigned short* __restrict__ wq,
                                               float* __restrict__ opart) {
  const int t = threadIdx.x;
  const int lane = t & 63;
  const int wv = t >> 6;                   // 0..1
  const int bid = blockIdx.x;              // cs*1152 + nb ; 2304 total
  const int cs = bid / 1152;
  const int nb = bid - cs * 1152;
  const int n0 = nb * 32;
  const int b = n0 / SP;
  const int sp0 = n0 - b * SP;

  const int posl = lane & 15;
  const int quad = lane >> 4;
  const int q = sp0 + wv * 16 + posl;          // this lane's output position
  const int d = q / PLANE;
  const int rp = q - d * PLANE;
  const int h = rp / 48;
  const int w = rp - h * 48;
  const int grow = b * SP + q;                 // global row in xTh

  const unsigned short* wbase = wq + cs * 3072 + posl * 32 + quad * 8;
  const int chof = cs * 32 + quad * 8;         // channel offset within row

  f32x4 acc[6];
#pragma unroll
  for (int mt = 0; mt < 6; ++mt) acc[mt] = f32x4{0.f, 0.f, 0.f, 0.f};

#pragma unroll
  for (int tap = 0; tap < 27; ++tap) {
    const int kd = tap / 9, kh = (tap % 9) / 3, kw = tap % 3;
    const int dd = d + kd - 1, hh = h + kh - 1, ww = w + kw - 1;
    const bool valid = ((unsigned)dd < 8u) & ((unsigned)hh < 48u) & ((unsigned)ww < 48u);
    const int delta = (kd - 1) * PLANE + (kh - 1) * 48 + (kw - 1);
    int row = grow + delta;
    row = min(max(row, 0), Bn * SP - 1);       // clamp: always a legal address
    // unconditional load, then mask to zero if the 3D tap is out of bounds
    uint4 bu = *reinterpret_cast<const uint4*>(xTh + (size_t)row * 64 + chof);
    const unsigned m = valid ? 0xFFFFFFFFu : 0u;
    bu.x &= m; bu.y &= m; bu.z &= m; bu.w &= m;
    half8 bf = __builtin_bit_cast(half8, bu);
    const unsigned short* wt = wbase + tap * 6144;
#pragma unroll
    for (int mt = 0; mt < 6; ++mt) {
      half8 af = *reinterpret_cast<const half8*>(wt + mt * 512);
      acc[mt] = __builtin_amdgcn_mfma_f32_16x16x32_f16(af, bf, acc[mt], 0, 0, 0);
    }
  }

  // opart[cs][b][ch][colp], ch<81
  const int colp = sp0 + wv * 16 + posl;
  float* pp = opart + (size_t)(cs * 2 + b) * 81 * SP;
#pragma unroll
  for (int mt = 0; mt < 6; ++mt) {
#pragma unroll
    for (int reg = 0; reg < 4; ++reg) {
      int ch = mt * 16 + quad * 4 + reg;
      if (ch < 81)
        pp[(size_t)ch * SP + colp] = acc[mt][reg];
    }
  }
}

// offT[b][k][p] = float4(pd, ph, pw, 0) with base grid + conv bias folded in.
__global__ __launch_bounds__(256) void k_offT(const float* __restrict__ opart,
                                              const float* __restrict__ cb,
                                              float* __restrict__ offT) {
  int i = blockIdx.x * 256 + threadIdx.x;  // 2*27*4608 = 248,832
  int p4 = i % (SP / 4);
  int k = (i / (SP / 4)) % 27;
  int b = i / ((SP / 4) * 27);
  int kd = k / 9, kh = (k % 9) / 3, kw = k % 3;

  const float4* op4 = (const float4*)opart;
  float4 s[3];
#pragma unroll
  for (int dim = 0; dim < 3; ++dim) {
    int ch = dim * 27 + k;
    size_t base = (size_t)(b * 81 + ch) * (SP / 4) + p4;
    float4 v0 = op4[base];
    float4 v1 = op4[base + (size_t)2 * 81 * (SP / 4)];
    float bb = cb[ch];
    s[dim] = float4{v0.x + v1.x + bb, v0.y + v1.y + bb, v0.z + v1.z + bb,
                    v0.w + v1.w + bb};
  }
  float4* o4 = (float4*)offT + ((size_t)(b * 27 + k) * SP + p4 * 4);
#pragma unroll
  for (int e = 0; e < 4; ++e) {
    int p = p4 * 4 + e;
    int d = p / PLANE;
    int r = p - d * PLANE;
    int h = r / 48;
    int wp = r - h * 48;
    float se0 = (e == 0) ? s[0].x : (e == 1) ? s[0].y : (e == 2) ? s[0].z : s[0].w;
    float se1 = (e == 0) ? s[1].x : (e == 1) ? s[1].y : (e == 2) ? s[1].z : s[1].w;
    float se2 = (e == 0) ? s[2].x : (e == 1) ? s[2].y : (e == 2) ? s[2].z : s[2].w;
    o4[e] = float4{se0 + (float)(d + kd - 1), se1 + (float)(h + kh - 1),
                   se2 + (float)(wp + kw - 1), 0.f};
  }
}

// Fused gather + MFMA GEMM (R14 structure, unchanged: 74 µs plateau, parked).
__global__ __launch_bounds__(128, 8) void k_mainp(const unsigned short* __restrict__ xTh,
                                                  const float* __restrict__ offT,
                                                  const unsigned short* __restrict__ wTb,
                                                  float* __restrict__ part) {
  __shared__ __align__(16) unsigned scp[2][16 * 20];         // per-wave [pos16][20w]
  __shared__ __align__(16) unsigned short vals[2][16 * 72];  // per-wave [pos16][cin]

  const int t = threadIdx.x;
  const int lane = t & 63;
  const int wv = t >> 6;                         // 0..1
  const int bid = blockIdx.x;                    // kc*1152 + j
  const int kc = bid / 1152;
  const int j = bid - kc * 1152;
  const int tl = (j & 7) * 144 + (j >> 3);       // XCD-contiguous tiles
  const int b = tl / NT32;
  const int tile = tl - b * NT32;
  const int p0 = tile * 32;

  const char* xb8 = (const char*)(xTh + (size_t)b * SP * 64);
  const float4* offTb = (const float4*)offT + (size_t)b * 27 * SP;

  const int posl = lane & 15;
  const int quad = lane >> 4;
  const int p = p0 + wv * 16 + posl;             // this lane's position
  unsigned* myrow = &scp[wv][posl * 20];

  const int gpl0 = lane >> 3;   // gather: row base 0..7
  const int gchg = lane & 7;    // gather: 8-channel chunk

  f32x4 acc[4];
#pragma unroll
  for (int mt = 0; mt < 4; ++mt) acc[mt] = f32x4{0.f, 0.f, 0.f, 0.f};

  for (int kk = 0; kk < KPER; ++kk) {
    const int k = kc * KPER + kk;
    // ---- setup: corners 2*quad, 2*quad+1 of position p (offT pre-folded)
    {
      float4 o = offTb[(size_t)k * SP + p];
      float df = floorf(o.x), hf = floorf(o.y), wf = floorf(o.z);
      float fd = o.x - df, fh = o.y - hf, fw = o.z - wf;
      int d0 = (int)df, h0 = (int)hf, w0i = (int)wf;
      unsigned pk[4];
#pragma unroll
      for (int cc = 0; cc < 2; ++cc) {
        int c = quad * 2 + cc;
        int cd = c >> 2, ch = (c >> 1) & 1, cwb = c & 1;
        int di = d0 + cd, hi = h0 + ch, wi = w0i + cwb;
        bool v = ((unsigned)di < 8u) && ((unsigned)hi < 48u) && ((unsigned)wi < 48u);
        float wg = (cd ? fd : 1.f - fd) * (ch ? fh : 1.f - fh) * (cwb ? fw : 1.f - fw);
        int dic = min(max(di, 0), 7), hic = min(max(hi, 0), 47), wic = min(max(wi, 0), 47);
        unsigned hs = (unsigned)f2h(v ? wg : 0.f);
        pk[cc * 2] = (unsigned)((dic * 48 + hic) * 48 + wic);
        pk[cc * 2 + 1] = hs | (hs << 16);
      }
      *reinterpret_cast<uint4*>(myrow + quad * 4) = uint4{pk[0], pk[1], pk[2], pk[3]};
    }
    // ---- gather: 2 units/lane, rows gpl0 and gpl0+8 (same-wave LDS ordering)
#pragma unroll
    for (int u = 0; u < 2; ++u) {
      const int pl = gpl0 + u * 8;
      const unsigned* sp = &scp[wv][pl * 20];
      const uint4 m0 = *reinterpret_cast<const uint4*>(sp + 0);
      const uint4 m1 = *reinterpret_cast<const uint4*>(sp + 4);
      const uint4 m2 = *reinterpret_cast<const uint4*>(sp + 8);
      const uint4 m3 = *reinterpret_cast<const uint4*>(sp + 12);
      const int cof = gchg << 4;
      uint4 q0 = *reinterpret_cast<const uint4*>(xb8 + (((size_t)m0.x << 7) + cof));
      uint4 q1 = *reinterpret_cast<const uint4*>(xb8 + (((size_t)m0.z << 7) + cof));
      uint4 q2 = *reinterpret_cast<const uint4*>(xb8 + (((size_t)m1.x << 7) + cof));
      uint4 q3 = *reinterpret_cast<const uint4*>(xb8 + (((size_t)m1.z << 7) + cof));
      uint4 q4 = *reinterpret_cast<const uint4*>(xb8 + (((size_t)m2.x << 7) + cof));
      uint4 q5 = *reinterpret_cast<const uint4*>(xb8 + (((size_t)m2.z << 7) + cof));
      uint4 q6 = *reinterpret_cast<const uint4*>(xb8 + (((size_t)m3.x << 7) + cof));
      uint4 q7 = *reinterpret_cast<const uint4*>(xb8 + (((size_t)m3.z << 7) + cof));
      __half2 a2[4];
#pragma unroll
      for (int e = 0; e < 4; ++e) a2[e] = u2h2(0u);
      __half2 w0 = u2h2(m0.y), w1 = u2h2(m0.w), w2 = u2h2(m1.y), w3 = u2h2(m1.w);
      __half2 w4 = u2h2(m2.y), w5 = u2h2(m2.w), w6 = u2h2(m3.y), w7 = u2h2(m3.w);
      a2[0] = __hfma2(u2h2(q0.x), w0, a2[0]); a2[1] = __hfma2(u2h2(q0.y), w0, a2[1]);
      a2[2] = __hfma2(u2h2(q0.z), w0, a2[2]); a2[3] = __hfma2(u2h2(q0.w), w0, a2[3]);
      a2[0] = __hfma2(u2h2(q1.x), w1, a2[0]); a2[1] = __hfma2(u2h2(q1.y), w1, a2[1]);
      a2[2] = __hfma2(u2h2(q1.z), w1, a2[2]); a2[3] = __hfma2(u2h2(q1.w), w1, a2[3]);
      a2[0] = __hfma2(u2h2(q2.x), w2, a2[0]); a2[1] = __hfma2(u2h2(q2.y), w2, a2[1]);
      a2[2] = __hfma2(u2h2(q2.z), w2, a2[2]); a2[3] = __hfma2(u2h2(q2.w), w2, a2[3]);
      a2[0] = __hfma2(u2h2(q3.x), w3, a2[0]); a2[1] = __hfma2(u2h2(q3.y), w3, a2[1]);
      a2[2] = __hfma2(u2h2(q3.z), w3, a2[2]); a2[3] = __hfma2(u2h2(q3.w), w3, a2[3]);
      a2[0] = __hfma2(u2h2(q4.x), w4, a2[0]); a2[1] = __hfma2(u2h2(q4.y), w4, a2[1]);
      a2[2] = __hfma2(u2h2(q4.z), w4, a2[2]); a2[3] = __hfma2(u2h2(q4.w), w4, a2[3]);
      a2[0] = __hfma2(u2h2(q5.x), w5, a2[0]); a2[1] = __hfma2(u2h2(q5.y), w5, a2[1]);
      a2[2] = __hfma2(u2h2(q5.z), w5, a2[2]); a2[3] = __hfma2(u2h2(q5.w), w5, a2[3]);
      a2[0] = __hfma2(u2h2(q6.x), w6, a2[0]); a2[1] = __hfma2(u2h2(q6.y), w6, a2[1]);
      a2[2] = __hfma2(u2h2(q6.z), w6, a2[2]); a2[3] = __hfma2(u2h2(q6.w), w6, a2[3]);
      a2[0] = __hfma2(u2h2(q7.x), w7, a2[0]); a2[1] = __hfma2(u2h2(q7.y), w7, a2[1]);
      a2[2] = __hfma2(u2h2(q7.z), w7, a2[2]); a2[3] = __hfma2(u2h2(q7.w), w7, a2[3]);
      *reinterpret_cast<uint4*>(&vals[wv][pl * 72 + gchg * 8]) =
          uint4{h22u(a2[0]), h22u(a2[1]), h22u(a2[2]), h22u(a2[3])};
    }
    // ---- MFMA: B-frag from this wave's own vals (same-wave ordering)
    {
      const unsigned short* wk = wTb + (size_t)k * 4096;
#pragma unroll
      for (int s = 0; s < 2; ++s) {
        half8 bfr = *reinterpret_cast<const half8*>(
            &vals[wv][posl * 72 + s * 32 + quad * 8]);
#pragma unroll
        for (int mt = 0; mt < 4; ++mt) {
          half8 afr = *reinterpret_cast<const half8*>(
              wk + mt * 1024 + s * 512 + posl * 32 + quad * 8);
          acc[mt] = __builtin_amdgcn_mfma_f32_16x16x32_f16(afr, bfr, acc[mt], 0, 0, 0);
        }
      }
    }
  }

  // part[kc][b][tile32][co][32]; co = mt*16+quad*4+reg, pos = wv*16+posl
  float* pp = part + ((size_t)(kc * 2 + b) * NT32 + tile) * 2048;
#pragma unroll
  for (int mt = 0; mt < 4; ++mt) {
#pragma unroll
    for (int reg = 0; reg < 4; ++reg) {
      int co = mt * 16 + quad * 4 + reg;
      pp[co * 32 + wv * 16 + posl] = acc[mt][reg];
    }
  }
}

// out[b][co][p] = bias[co] + sum_kc part[kc][b][tile32][co][pos]  (float4)
__global__ __launch_bounds__(256) void k_red(const float* __restrict__ part,
                                             const float* __restrict__ bias,
                                             float* __restrict__ out) {
  int i = blockIdx.x * 256 + threadIdx.x;  // 589,824 float4 units
  int p4 = i % (SP / 4);
  int co = (i / (SP / 4)) & 63;
  int b = i / ((SP / 4) * 64);
  int p = p4 * 4;
  int tile = p >> 5, pos = p & 31;
  size_t base = ((size_t)(b * NT32) + tile) * 2048 + co * 32 + pos;
  float4 s = *reinterpret_cast<const float4*>(&part[base]);
#pragma unroll
  for (int kc = 1; kc < KC; ++kc) {
    float4 v = *reinterpret_cast<const float4*>(
        &part[base + (size_t)kc * 2 * NT32 * 2048]);
    s.x += v.x; s.y += v.y; s.z += v.z; s.w += v.w;
  }
  float bb = bias[co];
  s.x += bb; s.y += bb; s.z += bb; s.w += bb;
  *reinterpret_cast<float4*>(&out[((size_t)(b * 64 + co)) * SP + p]) = s;
}

extern "C" void kernel_launch(void* const* d_in, const int* in_sizes, int n_in,
                              void* d_out, int out_size, void* d_ws, size_t ws_size,
                              hipStream_t stream) {
  const float* x = (const float*)d_in[0];
  const float* cw = (const float*)d_in[1];
  const float* cb = (const float*)d_in[2];
  const float* w = (const float*)d_in[3];
  const float* bias = (const float*)d_in[4];
  float* out = (float*)d_out;

  char* ws = (char*)d_ws;
  float* offT = (float*)ws;                                  // 15,925,248 B
  unsigned short* xTh = (unsigned short*)(ws + 15925248);    //  4,718,592 B
  unsigned short* wTb = (unsigned short*)(ws + 20643840);    //    221,184 B
  unsigned short* wq = (unsigned short*)(ws + 20865024);     //    331,776 B
  float* part = (float*)(ws + 21196800);                     // 28,311,552 B
  float* opart = (float*)(ws + 49508352);                    // 23,887,872 B

  hipLaunchKernelGGL(k_prep, dim3(10296), dim3(256), 0, stream, x, w, cw, xTh, wTb, wq);
  hipLaunchKernelGGL(k_offm3, dim3(CS * 1152), dim3(128), 0, stream, xTh, wq, opart);
  hipLaunchKernelGGL(k_offT, dim3(972), dim3(256), 0, stream, opart, cb, offT);
  hipLaunchKernelGGL(k_mainp, dim3(KC * 1152), dim3(128), 0, stream, xTh, offT, wTb, part);
  hipLaunchKernelGGL(k_red, dim3(2304), dim3(256), 0, stream, part, bias, out);
}